// Round 5
// baseline (290.044 us; speedup 1.0000x reference)
//
#include <hip/hip_runtime.h>
#include <hip/hip_bf16.h>

#define NQ 8
#define DIM 256
#define NB 16
#define NW 16
#define VOCABN 50257
#define EMBN 512

// ---------- wave64 helpers ----------
__device__ __forceinline__ float2 shfl2(float2 a, int m){
  float2 r; r.x = __shfl_xor(a.x, m, 64); r.y = __shfl_xor(a.y, m, 64); return r;
}
__device__ __forceinline__ float wave_sum(float x){
  #pragma unroll
  for (int off = 1; off < 64; off <<= 1) x += __shfl_xor(x, off, 64);
  return x;
}

// RY pair update: a0' = c a0 - s a1 ; a1' = s a0 + c a1
__device__ __forceinline__ void ry_pair(float2& a0, float2& a1, float c, float s){
  float2 n0 = make_float2(c*a0.x - s*a1.x, c*a0.y - s*a1.y);
  float2 n1 = make_float2(s*a0.x + c*a1.x, s*a0.y + c*a1.y);
  a0 = n0; a1 = n1;
}
// RX pair update: a0' = c a0 - i s a1 ; a1' = -i s a0 + c a1
__device__ __forceinline__ void rx_pair(float2& a0, float2& a1, float c, float s){
  float2 n0 = make_float2(c*a0.x + s*a1.y, c*a0.y - s*a1.x);
  float2 n1 = make_float2(c*a1.x + s*a0.y, c*a1.y - s*a0.x);
  a0 = n0; a1 = n1;
}

// State layout: lane holds amplitudes idx = (r<<6)|lane, r=0..3.
// idx bit k: k<6 -> lane bit, k=6 -> r bit0, k=7 -> r bit1. Qubit q <-> bit (7-q).
__device__ __forceinline__ void apply_gate(float2 v[4], int lane, int kind, int cbit, int tbit,
                                           float c, float s){
  if (kind == 0){ // RY
    if (tbit == 7){ ry_pair(v[0], v[2], c, s); ry_pair(v[1], v[3], c, s); }
    else if (tbit == 6){ ry_pair(v[0], v[1], c, s); ry_pair(v[2], v[3], c, s); }
    else {
      int m = 1 << tbit;
      #pragma unroll
      for (int r = 0; r < 4; ++r){
        float2 w = shfl2(v[r], m);
        float sg = (lane & m) ? s : -s;
        v[r] = make_float2(c*v[r].x + sg*w.x, c*v[r].y + sg*w.y);
      }
    }
  } else { // CRX
    if (tbit >= 6){
      if (cbit >= 6){
        if (cbit == 7) rx_pair(v[2], v[3], c, s);
        else           rx_pair(v[1], v[3], c, s);
      } else {
        int cm = 1 << cbit;
        if (lane & cm){
          if (tbit == 7){ rx_pair(v[0], v[2], c, s); rx_pair(v[1], v[3], c, s); }
          else          { rx_pair(v[0], v[1], c, s); rx_pair(v[2], v[3], c, s); }
        }
      }
    } else {
      int m = 1 << tbit;
      if (cbit >= 6){
        int r0 = (cbit == 6) ? 1 : 2;
        float2 w0 = shfl2(v[r0], m);
        float2 w1 = shfl2(v[3], m);
        v[r0] = make_float2(c*v[r0].x + s*w0.y, c*v[r0].y - s*w0.x);
        v[3]  = make_float2(c*v[3].x  + s*w1.y, c*v[3].y  - s*w1.x);
      } else {
        int cm = 1 << cbit;
        bool act = (lane & cm) != 0;
        #pragma unroll
        for (int r = 0; r < 4; ++r){
          float2 w = shfl2(v[r], m);
          if (act) v[r] = make_float2(c*v[r].x + s*w.y, c*v[r].y - s*w.x);
        }
      }
    }
  }
}

// One sim14 layer = 32 gates. cs[g] = (cos(th/2), sin(th/2)).
__device__ __forceinline__ void sim32(float2 v[4], int lane, const float2* __restrict__ cs){
  constexpr int KIND[32] = {0,0,0,0,0,0,0,0, 1,1,1,1,1,1,1,1, 0,0,0,0,0,0,0,0, 1,1,1,1,1,1,1,1};
  constexpr int CB[32]   = {0,0,0,0,0,0,0,0, 0,1,2,3,4,5,6,7, 0,0,0,0,0,0,0,0, 0,7,6,5,4,3,2,1};
  constexpr int TB[32]   = {7,6,5,4,3,2,1,0, 7,0,1,2,3,4,5,6, 7,6,5,4,3,2,1,0, 1,0,7,6,5,4,3,2};
  #pragma unroll
  for (int g = 0; g < 32; ++g){
    float2 p = cs[g];
    apply_gate(v, lane, KIND[g], CB[g], TB[g], p.x, p.y);
  }
}

// measurement of one qubit with bit t: wave-reduced xr, xi, zz
__device__ __forceinline__ void measure_one(const float2 v[4], int lane, int t,
                                            float& xr, float& xi, float& zz){
  xr = 0.f; xi = 0.f; zz = 0.f;
  if (t == 7){
    #pragma unroll
    for (int r = 0; r < 2; ++r){
      float2 a0 = v[r], a1 = v[r+2];
      xr += a0.x*a1.x + a0.y*a1.y;
      xi += a0.x*a1.y - a0.y*a1.x;
      zz += (a0.x*a0.x + a0.y*a0.y) - (a1.x*a1.x + a1.y*a1.y);
    }
  } else if (t == 6){
    #pragma unroll
    for (int r = 0; r < 4; r += 2){
      float2 a0 = v[r], a1 = v[r+1];
      xr += a0.x*a1.x + a0.y*a1.y;
      xi += a0.x*a1.y - a0.y*a1.x;
      zz += (a0.x*a0.x + a0.y*a0.y) - (a1.x*a1.x + a1.y*a1.y);
    }
  } else {
    int m = 1 << t;
    #pragma unroll
    for (int r = 0; r < 4; ++r){
      float2 a = v[r];
      float2 w = shfl2(a, m);
      if (!(lane & m)){
        xr += a.x*w.x + a.y*w.y;
        xi += a.x*w.y - a.y*w.x;
        zz += (a.x*a.x + a.y*a.y) - (w.x*w.x + w.y*w.y);
      }
    }
  }
  xr = wave_sum(xr); xi = wave_sum(xi); zz = wave_sum(zz);
}

// ---------- fused prep + degree 1 (256 blocks x 64 threads) ----------
__global__ __launch_bounds__(64) void k_pd1(
    const int* __restrict__ x, const float* __restrict__ embW,
    const float* __restrict__ e2rW, const float* __restrict__ e2rb,
    const float* __restrict__ mixri, const float* __restrict__ qff,
    float* __restrict__ wcs, float* __restrict__ qcs, float2* __restrict__ S1)
{
  const int p = blockIdx.x;    // 0..255 = b*16+w
  const int j = threadIdx.x;   // rotation index 0..63
  __shared__ float2 cs[64];

  { // angle j = emb . e2rW[j] + b[j]
    const int tok = x[p];
    const float4* er = (const float4*)(embW + (size_t)tok * EMBN);
    const float4* wr = (const float4*)(e2rW + (size_t)j * EMBN);
    float acc = e2rb[j];
    #pragma unroll 4
    for (int k = 0; k < EMBN/4; ++k){
      float4 e = er[k], w4 = wr[k];
      acc += e.x*w4.x + e.y*w4.y + e.z*w4.z + e.w*w4.w;
    }
    float th = 0.5f * acc;
    float2 c2 = make_float2(cosf(th), sinf(th));
    cs[j] = c2;
    ((float2*)wcs)[p*64 + j] = c2;          // for degrees 2,3
    if (p == 0 && j < 32){ float t = 0.5f * qff[j]; ((float2*)qcs)[j] = make_float2(cosf(t), sinf(t)); }
  }
  __syncthreads();

  const int lane = j;
  float2 v[4];
  v[0] = make_float2(lane == 0 ? 1.f : 0.f, 0.f);
  v[1] = v[2] = v[3] = make_float2(0.f, 0.f);
  sim32(v, lane, cs);
  sim32(v, lane, cs + 32);

  // coeff computed redundantly per thread (16 small ops)
  float ssum = 0.f;
  #pragma unroll
  for (int i = 0; i < 16; ++i){
    float mr = mixri[2*i], mi = mixri[2*i+1];
    ssum += sqrtf(mr*mr + mi*mi);
  }
  ssum = fmaxf(ssum, 1e-12f);
  const int w = p & 15;
  const float2 coef = make_float2(mixri[2*w]/ssum, mixri[2*w+1]/ssum);
  #pragma unroll
  for (int r = 0; r < 4; ++r){
    float2 a = v[r];
    S1[p*DIM + ((r<<6) | lane)] = make_float2(coef.x*a.x - coef.y*a.y, coef.x*a.y + coef.y*a.x);
  }
}

// ---------- degree d (d=2,3): reduce previous staging -> circuit -> staging ----------
__global__ __launch_bounds__(64) void k_deg(
    const float2* __restrict__ Sin, float2* __restrict__ Sout,
    const float* __restrict__ wcs, const float* __restrict__ mixri,
    const float* __restrict__ poly, float2* __restrict__ accs, int dprev)
{
  const int p = blockIdx.x, lane = threadIdx.x;
  const int b = p >> 4, w = p & 15;
  float2 v[4];
  v[0] = v[1] = v[2] = v[3] = make_float2(0.f, 0.f);
  const float2* base = Sin + b*NW*DIM;
  #pragma unroll
  for (int ww = 0; ww < NW; ++ww){
    #pragma unroll
    for (int r = 0; r < 4; ++r){
      float2 a = base[ww*DIM + ((r<<6) | lane)];
      v[r].x += a.x; v[r].y += a.y;
    }
  }
  if (w == 0){
    const float pd = poly[dprev];
    #pragma unroll
    for (int r = 0; r < 4; ++r){
      const int idx = (r<<6) | lane;
      float2 cur = make_float2(pd*v[r].x, pd*v[r].y);
      if (dprev == 1){
        if (idx == 0) cur.x += poly[0];
        accs[b*DIM + idx] = cur;
      } else {
        float2 old = accs[b*DIM + idx];
        accs[b*DIM + idx] = make_float2(old.x + cur.x, old.y + cur.y);
      }
    }
  }
  const float2* mycs = ((const float2*)wcs) + p*64;
  sim32(v, lane, mycs);
  sim32(v, lane, mycs + 32);
  float ssum = 0.f;
  #pragma unroll
  for (int i = 0; i < 16; ++i){
    float mr = mixri[2*i], mi = mixri[2*i+1];
    ssum += sqrtf(mr*mr + mi*mi);
  }
  ssum = fmaxf(ssum, 1e-12f);
  const float2 coef = make_float2(mixri[2*w]/ssum, mixri[2*w+1]/ssum);
  #pragma unroll
  for (int r = 0; r < 4; ++r){
    float2 a = v[r];
    Sout[p*DIM + ((r<<6) | lane)] = make_float2(coef.x*a.x - coef.y*a.y, coef.x*a.y + coef.y*a.x);
  }
}

// ---------- final: mix, norm, qff circuit, measure, ff1 ----------
__global__ __launch_bounds__(512) void k_final(
    const float2* __restrict__ Sin, const float2* __restrict__ accs,
    const float* __restrict__ poly, const float* __restrict__ qcs,
    const float* __restrict__ ff1W, const float* __restrict__ ff1b,
    float* __restrict__ hT, float* __restrict__ fprobs)
{
  const int b = blockIdx.x, tid = threadIdx.x;
  const int w = tid >> 6, lane = tid & 63;
  __shared__ float2 work[DIM];
  __shared__ float  red[8];
  __shared__ float  exps[24];
  __shared__ float  inv_s;
  __shared__ float  ff1_lds[EMBN*24];   // 48 KB

  { // stage ff1W coalesced: 3072 float4 over 512 threads
    const float4* f4 = (const float4*)ff1W;
    float4* d4 = (float4*)ff1_lds;
    #pragma unroll
    for (int i = 0; i < 6; ++i) d4[i*512 + tid] = f4[i*512 + tid];
  }
  const float psum = fabsf(poly[0]) + fabsf(poly[1]) + fabsf(poly[2]) + fabsf(poly[3]);
  float ssl = 0.f;
  if (tid < DIM){
    float2 s = make_float2(0.f, 0.f);
    const float2* base = Sin + b*NW*DIM;
    #pragma unroll
    for (int ww = 0; ww < NW; ++ww){ float2 a = base[ww*DIM + tid]; s.x += a.x; s.y += a.y; }
    float2 ac = accs[b*DIM + tid];
    const float p3 = poly[3];
    s = make_float2((ac.x + p3*s.x)/psum, (ac.y + p3*s.y)/psum);
    work[tid] = s;
    ssl = s.x*s.x + s.y*s.y;
  }
  ssl = wave_sum(ssl);
  if (lane == 0) red[w] = ssl;
  __syncthreads();
  if (tid == 0){
    float fp = sqrtf(red[0] + red[1] + red[2] + red[3]);
    fprobs[b] = fp;
    inv_s = 1.f / fmaxf(fp, 1e-12f);
  }
  __syncthreads();
  { // waves 0..7 redundantly run the qff circuit; wave w measures qubit w
    const float inv = inv_s;
    float2 v[4];
    #pragma unroll
    for (int r = 0; r < 4; ++r){
      float2 m = work[(r<<6) | lane];
      v[r] = make_float2(m.x*inv, m.y*inv);
    }
    sim32(v, lane, (const float2*)qcs);
    float xr, xi, zz;
    measure_one(v, lane, 7 - w, xr, xi, zz);
    if (lane == 0){ exps[w] = 2.f*xr; exps[8+w] = 2.f*xi; exps[16+w] = zz; }
  }
  __syncthreads();
  float a = ff1b[tid];
  const float* wr = ff1_lds + tid*24;
  #pragma unroll
  for (int m2 = 0; m2 < 24; ++m2) a += exps[m2]*wr[m2];
  hT[tid*NB + b] = fmaxf(a, 0.f);   // k-major hT[k][b]
}

// ---------- k_out: 128 rows/block, 2 rows/thread, 4 K-quarters (393 blocks) ----------
// h LDS broadcasts amortized over 2 rows: per iter 16 ds_read_b128 (192 cyc)
// feed 128 FMA (256 cyc) -> VALU-bound. Reduction reuses the hT LDS region.
__global__ __launch_bounds__(256) void k_out(
    const float* __restrict__ hT, const float* __restrict__ ff2W,
    const float* __restrict__ ff2b, const float* __restrict__ fprobs,
    float* __restrict__ out)
{
  __shared__ float4 hs[2048];   // 32 KB: hT[k][b] as b-quads; reused for reduction
  const int tid = threadIdx.x;
  const int q = tid >> 6;       // K-quarter
  const int lane = tid & 63;

  if (blockIdx.x == 0 && tid == 0){
    float s = 0.f;
    #pragma unroll
    for (int i = 0; i < 16; ++i) s += fprobs[i];
    out[(size_t)NB*VOCABN] = s * (1.f/16.f);
  }

  { // stage hT -> LDS (coalesced)
    const float4* hT4 = (const float4*)hT;
    #pragma unroll
    for (int i = 0; i < 8; ++i) hs[i*256 + tid] = hT4[i*256 + tid];
  }
  __syncthreads();

  const int base = blockIdx.x * 128;
  const int r0 = base + lane;
  const int r1 = r0 + 64;
  const int rc0 = min(r0, VOCABN-1);   // clamp for tail-block loads
  const int rc1 = min(r1, VOCABN-1);

  float4 acc0[4], acc1[4];
  #pragma unroll
  for (int i = 0; i < 4; ++i){ acc0[i] = make_float4(0,0,0,0); acc1[i] = make_float4(0,0,0,0); }

  const float4* w0 = (const float4*)(ff2W + (size_t)rc0 * EMBN) + q*32;
  const float4* w1 = (const float4*)(ff2W + (size_t)rc1 * EMBN) + q*32;

  #pragma unroll 4
  for (int c = 0; c < 32; ++c){
    float4 wa = w0[c];
    float4 wb = w1[c];
    const int k0 = (q*128 + c*4) << 2;   // float4 index of (k, bq=0)
    #pragma unroll
    for (int kk = 0; kk < 4; ++kk){
      const float wka = (kk==0) ? wa.x : (kk==1) ? wa.y : (kk==2) ? wa.z : wa.w;
      const float wkb = (kk==0) ? wb.x : (kk==1) ? wb.y : (kk==2) ? wb.z : wb.w;
      #pragma unroll
      for (int bq = 0; bq < 4; ++bq){
        float4 hh = hs[k0 + kk*4 + bq];
        acc0[bq].x += wka*hh.x; acc0[bq].y += wka*hh.y;
        acc0[bq].z += wka*hh.z; acc0[bq].w += wka*hh.w;
        acc1[bq].x += wkb*hh.x; acc1[bq].y += wkb*hh.y;
        acc1[bq].z += wkb*hh.z; acc1[bq].w += wkb*hh.w;
      }
    }
  }
  __syncthreads();   // done reading hs

  // cross-quarter reduction in reused LDS: red[q-1][lane][32] with +1 pad (stride 33)
  float* redf = (float*)hs;
  if (q > 0){
    float* dst = redf + (q-1)*2112 + lane*33;
    #pragma unroll
    for (int bq = 0; bq < 4; ++bq){
      dst[bq*4+0] = acc0[bq].x; dst[bq*4+1] = acc0[bq].y;
      dst[bq*4+2] = acc0[bq].z; dst[bq*4+3] = acc0[bq].w;
      dst[16+bq*4+0] = acc1[bq].x; dst[16+bq*4+1] = acc1[bq].y;
      dst[16+bq*4+2] = acc1[bq].z; dst[16+bq*4+3] = acc1[bq].w;
    }
  }
  __syncthreads();
  if (q == 0){
    #pragma unroll
    for (int qq = 0; qq < 3; ++qq){
      const float* src = redf + qq*2112 + lane*33;
      #pragma unroll
      for (int bq = 0; bq < 4; ++bq){
        acc0[bq].x += src[bq*4+0]; acc0[bq].y += src[bq*4+1];
        acc0[bq].z += src[bq*4+2]; acc0[bq].w += src[bq*4+3];
        acc1[bq].x += src[16+bq*4+0]; acc1[bq].y += src[16+bq*4+1];
        acc1[bq].z += src[16+bq*4+2]; acc1[bq].w += src[16+bq*4+3];
      }
    }
    if (r0 < VOCABN){
      const float bias = ff2b[r0];
      #pragma unroll
      for (int bq = 0; bq < 4; ++bq){
        out[(size_t)(bq*4+0)*VOCABN + r0] = acc0[bq].x + bias;
        out[(size_t)(bq*4+1)*VOCABN + r0] = acc0[bq].y + bias;
        out[(size_t)(bq*4+2)*VOCABN + r0] = acc0[bq].z + bias;
        out[(size_t)(bq*4+3)*VOCABN + r0] = acc0[bq].w + bias;
      }
    }
    if (r1 < VOCABN){
      const float bias = ff2b[r1];
      #pragma unroll
      for (int bq = 0; bq < 4; ++bq){
        out[(size_t)(bq*4+0)*VOCABN + r1] = acc1[bq].x + bias;
        out[(size_t)(bq*4+1)*VOCABN + r1] = acc1[bq].y + bias;
        out[(size_t)(bq*4+2)*VOCABN + r1] = acc1[bq].z + bias;
        out[(size_t)(bq*4+3)*VOCABN + r1] = acc1[bq].w + bias;
      }
    }
  }
}

extern "C" void kernel_launch(void* const* d_in, const int* in_sizes, int n_in,
                              void* d_out, int out_size, void* d_ws, size_t ws_size,
                              hipStream_t stream)
{
  const int*   x     = (const int*)  d_in[0];
  const float* embW  = (const float*)d_in[1];
  const float* e2rW  = (const float*)d_in[2];
  const float* e2rb  = (const float*)d_in[3];
  const float* poly  = (const float*)d_in[4];
  const float* mixri = (const float*)d_in[5];
  const float* qff   = (const float*)d_in[6];
  const float* ff1W  = (const float*)d_in[7];
  const float* ff1b  = (const float*)d_in[8];
  const float* ff2W  = (const float*)d_in[9];
  const float* ff2b  = (const float*)d_in[10];
  float* out = (float*)d_out;
  float* ws  = (float*)d_ws;

  float*  wcs    = ws;             // 32768 floats
  float*  qcs    = ws + 32768;     // 64
  float*  hT     = ws + 32832;     // 8192
  float*  fprobs = ws + 41024;     // 16
  float2* accs   = (float2*)(ws + 41040);   // 8192 floats
  float2* S1     = (float2*)(ws + 49232);   // 131072 floats
  float2* S2     = (float2*)(ws + 180304);  // 131072 floats

  k_pd1  <<<256, 64, 0, stream>>>(x, embW, e2rW, e2rb, mixri, qff, wcs, qcs, S1);
  k_deg  <<<256, 64, 0, stream>>>(S1, S2, wcs, mixri, poly, accs, 1);
  k_deg  <<<256, 64, 0, stream>>>(S2, S1, wcs, mixri, poly, accs, 2);
  k_final<<<NB, 512, 0, stream>>>(S1, accs, poly, qcs, ff1W, ff1b, hT, fprobs);
  k_out  <<<(VOCABN + 127)/128, 256, 0, stream>>>(hT, ff2W, ff2b, fprobs, out);
}

// Round 6
// 278.043 us; speedup vs baseline: 1.0432x; 1.0432x over previous
//
#include <hip/hip_runtime.h>
#include <hip/hip_bf16.h>

#define NQ 8
#define DIM 256
#define NB 16
#define NW 16
#define VOCABN 50257
#define EMBN 512
#define NTILES ((VOCABN + 15) / 16)   // 3142

typedef __attribute__((ext_vector_type(8))) short short8;
typedef __attribute__((ext_vector_type(4))) float f32x4;

// ---------- wave64 helpers ----------
__device__ __forceinline__ float2 shfl2(float2 a, int m){
  float2 r; r.x = __shfl_xor(a.x, m, 64); r.y = __shfl_xor(a.y, m, 64); return r;
}
__device__ __forceinline__ float wave_sum(float x){
  #pragma unroll
  for (int off = 1; off < 64; off <<= 1) x += __shfl_xor(x, off, 64);
  return x;
}
__device__ __forceinline__ short f2bf(float f){
  __hip_bfloat16 h = __float2bfloat16(f);
  return __builtin_bit_cast(short, h);
}

// RY pair update: a0' = c a0 - s a1 ; a1' = s a0 + c a1
__device__ __forceinline__ void ry_pair(float2& a0, float2& a1, float c, float s){
  float2 n0 = make_float2(c*a0.x - s*a1.x, c*a0.y - s*a1.y);
  float2 n1 = make_float2(s*a0.x + c*a1.x, s*a0.y + c*a1.y);
  a0 = n0; a1 = n1;
}
// RX pair update: a0' = c a0 - i s a1 ; a1' = -i s a0 + c a1
__device__ __forceinline__ void rx_pair(float2& a0, float2& a1, float c, float s){
  float2 n0 = make_float2(c*a0.x + s*a1.y, c*a0.y - s*a1.x);
  float2 n1 = make_float2(c*a1.x + s*a0.y, c*a1.y - s*a0.x);
  a0 = n0; a1 = n1;
}

// State layout: lane holds amplitudes idx = (r<<6)|lane, r=0..3.
// idx bit k: k<6 -> lane bit, k=6 -> r bit0, k=7 -> r bit1. Qubit q <-> bit (7-q).
__device__ __forceinline__ void apply_gate(float2 v[4], int lane, int kind, int cbit, int tbit,
                                           float c, float s){
  if (kind == 0){ // RY
    if (tbit == 7){ ry_pair(v[0], v[2], c, s); ry_pair(v[1], v[3], c, s); }
    else if (tbit == 6){ ry_pair(v[0], v[1], c, s); ry_pair(v[2], v[3], c, s); }
    else {
      int m = 1 << tbit;
      #pragma unroll
      for (int r = 0; r < 4; ++r){
        float2 w = shfl2(v[r], m);
        float sg = (lane & m) ? s : -s;
        v[r] = make_float2(c*v[r].x + sg*w.x, c*v[r].y + sg*w.y);
      }
    }
  } else { // CRX
    if (tbit >= 6){
      if (cbit >= 6){
        if (cbit == 7) rx_pair(v[2], v[3], c, s);
        else           rx_pair(v[1], v[3], c, s);
      } else {
        int cm = 1 << cbit;
        if (lane & cm){
          if (tbit == 7){ rx_pair(v[0], v[2], c, s); rx_pair(v[1], v[3], c, s); }
          else          { rx_pair(v[0], v[1], c, s); rx_pair(v[2], v[3], c, s); }
        }
      }
    } else {
      int m = 1 << tbit;
      if (cbit >= 6){
        int r0 = (cbit == 6) ? 1 : 2;
        float2 w0 = shfl2(v[r0], m);
        float2 w1 = shfl2(v[3], m);
        v[r0] = make_float2(c*v[r0].x + s*w0.y, c*v[r0].y - s*w0.x);
        v[3]  = make_float2(c*v[3].x  + s*w1.y, c*v[3].y  - s*w1.x);
      } else {
        int cm = 1 << cbit;
        bool act = (lane & cm) != 0;
        #pragma unroll
        for (int r = 0; r < 4; ++r){
          float2 w = shfl2(v[r], m);
          if (act) v[r] = make_float2(c*v[r].x + s*w.y, c*v[r].y - s*w.x);
        }
      }
    }
  }
}

// One sim14 layer = 32 gates. cs[g] = (cos(th/2), sin(th/2)).
__device__ __forceinline__ void sim32(float2 v[4], int lane, const float2* __restrict__ cs){
  constexpr int KIND[32] = {0,0,0,0,0,0,0,0, 1,1,1,1,1,1,1,1, 0,0,0,0,0,0,0,0, 1,1,1,1,1,1,1,1};
  constexpr int CB[32]   = {0,0,0,0,0,0,0,0, 0,1,2,3,4,5,6,7, 0,0,0,0,0,0,0,0, 0,7,6,5,4,3,2,1};
  constexpr int TB[32]   = {7,6,5,4,3,2,1,0, 7,0,1,2,3,4,5,6, 7,6,5,4,3,2,1,0, 1,0,7,6,5,4,3,2};
  #pragma unroll
  for (int g = 0; g < 32; ++g){
    float2 p = cs[g];
    apply_gate(v, lane, KIND[g], CB[g], TB[g], p.x, p.y);
  }
}

// measurement of one qubit with bit t: wave-reduced xr, xi, zz
__device__ __forceinline__ void measure_one(const float2 v[4], int lane, int t,
                                            float& xr, float& xi, float& zz){
  xr = 0.f; xi = 0.f; zz = 0.f;
  if (t == 7){
    #pragma unroll
    for (int r = 0; r < 2; ++r){
      float2 a0 = v[r], a1 = v[r+2];
      xr += a0.x*a1.x + a0.y*a1.y;
      xi += a0.x*a1.y - a0.y*a1.x;
      zz += (a0.x*a0.x + a0.y*a0.y) - (a1.x*a1.x + a1.y*a1.y);
    }
  } else if (t == 6){
    #pragma unroll
    for (int r = 0; r < 4; r += 2){
      float2 a0 = v[r], a1 = v[r+1];
      xr += a0.x*a1.x + a0.y*a1.y;
      xi += a0.x*a1.y - a0.y*a1.x;
      zz += (a0.x*a0.x + a0.y*a0.y) - (a1.x*a1.x + a1.y*a1.y);
    }
  } else {
    int m = 1 << t;
    #pragma unroll
    for (int r = 0; r < 4; ++r){
      float2 a = v[r];
      float2 w = shfl2(a, m);
      if (!(lane & m)){
        xr += a.x*w.x + a.y*w.y;
        xi += a.x*w.y - a.y*w.x;
        zz += (a.x*a.x + a.y*a.y) - (w.x*w.x + w.y*w.y);
      }
    }
  }
  xr = wave_sum(xr); xi = wave_sum(xi); zz = wave_sum(zz);
}

// ---------- fused prep + degree 1 (256 blocks x 64 threads) ----------
__global__ __launch_bounds__(64) void k_pd1(
    const int* __restrict__ x, const float* __restrict__ embW,
    const float* __restrict__ e2rW, const float* __restrict__ e2rb,
    const float* __restrict__ mixri, const float* __restrict__ qff,
    float* __restrict__ wcs, float* __restrict__ qcs, float2* __restrict__ S1)
{
  const int p = blockIdx.x;    // 0..255 = b*16+w
  const int j = threadIdx.x;   // rotation index 0..63
  __shared__ float2 cs[64];

  { // angle j = emb . e2rW[j] + b[j]
    const int tok = x[p];
    const float4* er = (const float4*)(embW + (size_t)tok * EMBN);
    const float4* wr = (const float4*)(e2rW + (size_t)j * EMBN);
    float acc = e2rb[j];
    #pragma unroll 4
    for (int k = 0; k < EMBN/4; ++k){
      float4 e = er[k], w4 = wr[k];
      acc += e.x*w4.x + e.y*w4.y + e.z*w4.z + e.w*w4.w;
    }
    float th = 0.5f * acc;
    float2 c2 = make_float2(cosf(th), sinf(th));
    cs[j] = c2;
    ((float2*)wcs)[p*64 + j] = c2;          // for degrees 2,3
    if (p == 0 && j < 32){ float t = 0.5f * qff[j]; ((float2*)qcs)[j] = make_float2(cosf(t), sinf(t)); }
  }
  __syncthreads();

  const int lane = j;
  float2 v[4];
  v[0] = make_float2(lane == 0 ? 1.f : 0.f, 0.f);
  v[1] = v[2] = v[3] = make_float2(0.f, 0.f);
  sim32(v, lane, cs);
  sim32(v, lane, cs + 32);

  float ssum = 0.f;
  #pragma unroll
  for (int i = 0; i < 16; ++i){
    float mr = mixri[2*i], mi = mixri[2*i+1];
    ssum += sqrtf(mr*mr + mi*mi);
  }
  ssum = fmaxf(ssum, 1e-12f);
  const int w = p & 15;
  const float2 coef = make_float2(mixri[2*w]/ssum, mixri[2*w+1]/ssum);
  #pragma unroll
  for (int r = 0; r < 4; ++r){
    float2 a = v[r];
    S1[p*DIM + ((r<<6) | lane)] = make_float2(coef.x*a.x - coef.y*a.y, coef.x*a.y + coef.y*a.x);
  }
}

// ---------- degree d (d=2,3): reduce previous staging -> circuit -> staging ----------
__global__ __launch_bounds__(64) void k_deg(
    const float2* __restrict__ Sin, float2* __restrict__ Sout,
    const float* __restrict__ wcs, const float* __restrict__ mixri,
    const float* __restrict__ poly, float2* __restrict__ accs, int dprev)
{
  const int p = blockIdx.x, lane = threadIdx.x;
  const int b = p >> 4, w = p & 15;
  float2 v[4];
  v[0] = v[1] = v[2] = v[3] = make_float2(0.f, 0.f);
  const float2* base = Sin + b*NW*DIM;
  #pragma unroll
  for (int ww = 0; ww < NW; ++ww){
    #pragma unroll
    for (int r = 0; r < 4; ++r){
      float2 a = base[ww*DIM + ((r<<6) | lane)];
      v[r].x += a.x; v[r].y += a.y;
    }
  }
  if (w == 0){
    const float pd = poly[dprev];
    #pragma unroll
    for (int r = 0; r < 4; ++r){
      const int idx = (r<<6) | lane;
      float2 cur = make_float2(pd*v[r].x, pd*v[r].y);
      if (dprev == 1){
        if (idx == 0) cur.x += poly[0];
        accs[b*DIM + idx] = cur;
      } else {
        float2 old = accs[b*DIM + idx];
        accs[b*DIM + idx] = make_float2(old.x + cur.x, old.y + cur.y);
      }
    }
  }
  const float2* mycs = ((const float2*)wcs) + p*64;
  sim32(v, lane, mycs);
  sim32(v, lane, mycs + 32);
  float ssum = 0.f;
  #pragma unroll
  for (int i = 0; i < 16; ++i){
    float mr = mixri[2*i], mi = mixri[2*i+1];
    ssum += sqrtf(mr*mr + mi*mi);
  }
  ssum = fmaxf(ssum, 1e-12f);
  const float2 coef = make_float2(mixri[2*w]/ssum, mixri[2*w+1]/ssum);
  #pragma unroll
  for (int r = 0; r < 4; ++r){
    float2 a = v[r];
    Sout[p*DIM + ((r<<6) | lane)] = make_float2(coef.x*a.x - coef.y*a.y, coef.x*a.y + coef.y*a.x);
  }
}

// ---------- final: mix, norm, qff circuit, measure, ff1 -> h (bf16, b-major) ----------
__global__ __launch_bounds__(512) void k_final(
    const float2* __restrict__ Sin, const float2* __restrict__ accs,
    const float* __restrict__ poly, const float* __restrict__ qcs,
    const float* __restrict__ ff1W, const float* __restrict__ ff1b,
    __hip_bfloat16* __restrict__ hbf, float* __restrict__ fprobs)
{
  const int b = blockIdx.x, tid = threadIdx.x;
  const int w = tid >> 6, lane = tid & 63;
  __shared__ float2 work[DIM];
  __shared__ float  red[8];
  __shared__ float  exps[24];
  __shared__ float  inv_s;
  __shared__ float  ff1_lds[EMBN*24];   // 48 KB

  { // stage ff1W coalesced: 3072 float4 over 512 threads
    const float4* f4 = (const float4*)ff1W;
    float4* d4 = (float4*)ff1_lds;
    #pragma unroll
    for (int i = 0; i < 6; ++i) d4[i*512 + tid] = f4[i*512 + tid];
  }
  const float psum = fabsf(poly[0]) + fabsf(poly[1]) + fabsf(poly[2]) + fabsf(poly[3]);
  float ssl = 0.f;
  if (tid < DIM){
    float2 s = make_float2(0.f, 0.f);
    const float2* base = Sin + b*NW*DIM;
    #pragma unroll
    for (int ww = 0; ww < NW; ++ww){ float2 a = base[ww*DIM + tid]; s.x += a.x; s.y += a.y; }
    float2 ac = accs[b*DIM + tid];
    const float p3 = poly[3];
    s = make_float2((ac.x + p3*s.x)/psum, (ac.y + p3*s.y)/psum);
    work[tid] = s;
    ssl = s.x*s.x + s.y*s.y;
  }
  ssl = wave_sum(ssl);
  if (lane == 0) red[w] = ssl;
  __syncthreads();
  if (tid == 0){
    float fp = sqrtf(red[0] + red[1] + red[2] + red[3]);
    fprobs[b] = fp;
    inv_s = 1.f / fmaxf(fp, 1e-12f);
  }
  __syncthreads();
  { // waves 0..7 redundantly run the qff circuit; wave w measures qubit w
    const float inv = inv_s;
    float2 v[4];
    #pragma unroll
    for (int r = 0; r < 4; ++r){
      float2 m = work[(r<<6) | lane];
      v[r] = make_float2(m.x*inv, m.y*inv);
    }
    sim32(v, lane, (const float2*)qcs);
    float xr, xi, zz;
    measure_one(v, lane, 7 - w, xr, xi, zz);
    if (lane == 0){ exps[w] = 2.f*xr; exps[8+w] = 2.f*xi; exps[16+w] = zz; }
  }
  __syncthreads();
  float a = ff1b[tid];
  const float* wr = ff1_lds + tid*24;
  #pragma unroll
  for (int m2 = 0; m2 < 24; ++m2) a += exps[m2]*wr[m2];
  hbf[b*EMBN + tid] = __float2bfloat16(fmaxf(a, 0.f));   // b-major bf16 h
}

// ---------- k_out: MFMA GEMM  C[50257x16] = ff2W[50257x512] * h^T ----------
// One 16x16 tile per wave, 4 waves/block -> 786 blocks, ~12 waves/CU.
// B-fragments (h) in 64 VGPRs for the whole kernel; A loaded fp32 direct
// from ff2W (16-line dense per instr, 4 lanes/line) and cvt'd to bf16 in
// flight -> HBM traffic stays 103 MB. No LDS anywhere.
__global__ __launch_bounds__(256) void k_out(
    const __hip_bfloat16* __restrict__ hbf, const float* __restrict__ ff2W,
    const float* __restrict__ ff2b, const float* __restrict__ fprobs,
    float* __restrict__ out)
{
  const int tid = threadIdx.x;
  const int w = tid >> 6, lane = tid & 63;
  const int tile = blockIdx.x*4 + w;

  if (blockIdx.x == 0 && tid == 0){
    float s = 0.f;
    #pragma unroll
    for (int i = 0; i < 16; ++i) s += fprobs[i];
    out[(size_t)NB*VOCABN] = s * (1.f/16.f);
  }

  const int n = lane & 15;        // batch col (B) / row-in-tile (A)
  const int quad = lane >> 4;     // k-subchunk selector

  // B fragments: B[n=lane&15][k=quad*8+j] ; hbf is [b][k] b-major
  short8 bfrag[16];
  {
    const short* hb = (const short*)hbf + n*EMBN;
    #pragma unroll
    for (int f = 0; f < 16; ++f)
      bfrag[f] = *(const short8*)(hb + f*32 + quad*8);
  }

  if (tile >= NTILES) return;
  const int tbase = tile * 16;
  int row = tbase + n; if (row > VOCABN-1) row = VOCABN-1;   // clamp tail loads
  const float* ar = ff2W + (size_t)row * EMBN + quad*8;

  f32x4 acc = {0.f, 0.f, 0.f, 0.f};
  #pragma unroll
  for (int f = 0; f < 16; ++f){
    float4 a0 = *(const float4*)(ar + f*32);
    float4 a1 = *(const float4*)(ar + f*32 + 4);
    short8 af;
    af[0] = f2bf(a0.x); af[1] = f2bf(a0.y); af[2] = f2bf(a0.z); af[3] = f2bf(a0.w);
    af[4] = f2bf(a1.x); af[5] = f2bf(a1.y); af[6] = f2bf(a1.z); af[7] = f2bf(a1.w);
    acc = __builtin_amdgcn_mfma_f32_16x16x32_bf16(af, bfrag[f], acc, 0, 0, 0);
  }

  // C layout: col(n=batch) = lane&15, row(m) = quad*4 + r
  #pragma unroll
  for (int r = 0; r < 4; ++r){
    const int v = tbase + quad*4 + r;
    if (v < VOCABN)
      out[(size_t)n*VOCABN + v] = acc[r] + ff2b[v];
  }
}

extern "C" void kernel_launch(void* const* d_in, const int* in_sizes, int n_in,
                              void* d_out, int out_size, void* d_ws, size_t ws_size,
                              hipStream_t stream)
{
  const int*   x     = (const int*)  d_in[0];
  const float* embW  = (const float*)d_in[1];
  const float* e2rW  = (const float*)d_in[2];
  const float* e2rb  = (const float*)d_in[3];
  const float* poly  = (const float*)d_in[4];
  const float* mixri = (const float*)d_in[5];
  const float* qff   = (const float*)d_in[6];
  const float* ff1W  = (const float*)d_in[7];
  const float* ff1b  = (const float*)d_in[8];
  const float* ff2W  = (const float*)d_in[9];
  const float* ff2b  = (const float*)d_in[10];
  float* out = (float*)d_out;
  float* ws  = (float*)d_ws;

  float*  wcs    = ws;             // 32768 floats
  float*  qcs    = ws + 32768;     // 64
  __hip_bfloat16* hbf = (__hip_bfloat16*)(ws + 32832);  // 8192 bf16 = 4096 floats
  float*  fprobs = ws + 36928;     // 16
  float2* accs   = (float2*)(ws + 36944);   // 8192 floats
  float2* S1     = (float2*)(ws + 45136);   // 131072 floats
  float2* S2     = (float2*)(ws + 176208);  // 131072 floats

  k_pd1  <<<256, 64, 0, stream>>>(x, embW, e2rW, e2rb, mixri, qff, wcs, qcs, S1);
  k_deg  <<<256, 64, 0, stream>>>(S1, S2, wcs, mixri, poly, accs, 1);
  k_deg  <<<256, 64, 0, stream>>>(S2, S1, wcs, mixri, poly, accs, 2);
  k_final<<<NB, 512, 0, stream>>>(S1, accs, poly, qcs, ff1W, ff1b, hbf, fprobs);
  k_out  <<<(NTILES + 3)/4, 256, 0, stream>>>(hbf, ff2W, ff2b, fprobs, out);
}

// Round 7
// 263.882 us; speedup vs baseline: 1.0991x; 1.0537x over previous
//
#include <hip/hip_runtime.h>
#include <hip/hip_bf16.h>

#define NQ 8
#define DIM 256
#define NB 16
#define NW 16
#define VOCABN 50257
#define EMBN 512
#define NTILES ((VOCABN + 15) / 16)   // 3142

typedef __attribute__((ext_vector_type(8))) short short8;
typedef __attribute__((ext_vector_type(4))) float f32x4;

// ---------- wave64 helpers ----------
__device__ __forceinline__ float2 shfl2(float2 a, int m){
  float2 r; r.x = __shfl_xor(a.x, m, 64); r.y = __shfl_xor(a.y, m, 64); return r;
}
__device__ __forceinline__ float wave_sum(float x){
  #pragma unroll
  for (int off = 1; off < 64; off <<= 1) x += __shfl_xor(x, off, 64);
  return x;
}
__device__ __forceinline__ short f2bf(float f){
  __hip_bfloat16 h = __float2bfloat16(f);
  return __builtin_bit_cast(short, h);
}

// RY pair update: a0' = c a0 - s a1 ; a1' = s a0 + c a1
__device__ __forceinline__ void ry_pair(float2& a0, float2& a1, float c, float s){
  float2 n0 = make_float2(c*a0.x - s*a1.x, c*a0.y - s*a1.y);
  float2 n1 = make_float2(s*a0.x + c*a1.x, s*a0.y + c*a1.y);
  a0 = n0; a1 = n1;
}
// RX pair update: a0' = c a0 - i s a1 ; a1' = -i s a0 + c a1
__device__ __forceinline__ void rx_pair(float2& a0, float2& a1, float c, float s){
  float2 n0 = make_float2(c*a0.x + s*a1.y, c*a0.y - s*a1.x);
  float2 n1 = make_float2(c*a1.x + s*a0.y, c*a1.y - s*a0.x);
  a0 = n0; a1 = n1;
}

// State layout: lane holds amplitudes idx = (r<<6)|lane, r=0..3.
// idx bit k: k<6 -> lane bit, k=6 -> r bit0, k=7 -> r bit1. Qubit q <-> bit (7-q).
__device__ __forceinline__ void apply_gate(float2 v[4], int lane, int kind, int cbit, int tbit,
                                           float c, float s){
  if (kind == 0){ // RY
    if (tbit == 7){ ry_pair(v[0], v[2], c, s); ry_pair(v[1], v[3], c, s); }
    else if (tbit == 6){ ry_pair(v[0], v[1], c, s); ry_pair(v[2], v[3], c, s); }
    else {
      int m = 1 << tbit;
      #pragma unroll
      for (int r = 0; r < 4; ++r){
        float2 w = shfl2(v[r], m);
        float sg = (lane & m) ? s : -s;
        v[r] = make_float2(c*v[r].x + sg*w.x, c*v[r].y + sg*w.y);
      }
    }
  } else { // CRX
    if (tbit >= 6){
      if (cbit >= 6){
        if (cbit == 7) rx_pair(v[2], v[3], c, s);
        else           rx_pair(v[1], v[3], c, s);
      } else {
        int cm = 1 << cbit;
        if (lane & cm){
          if (tbit == 7){ rx_pair(v[0], v[2], c, s); rx_pair(v[1], v[3], c, s); }
          else          { rx_pair(v[0], v[1], c, s); rx_pair(v[2], v[3], c, s); }
        }
      }
    } else {
      int m = 1 << tbit;
      if (cbit >= 6){
        int r0 = (cbit == 6) ? 1 : 2;
        float2 w0 = shfl2(v[r0], m);
        float2 w1 = shfl2(v[3], m);
        v[r0] = make_float2(c*v[r0].x + s*w0.y, c*v[r0].y - s*w0.x);
        v[3]  = make_float2(c*v[3].x  + s*w1.y, c*v[3].y  - s*w1.x);
      } else {
        int cm = 1 << cbit;
        bool act = (lane & cm) != 0;
        #pragma unroll
        for (int r = 0; r < 4; ++r){
          float2 w = shfl2(v[r], m);
          if (act) v[r] = make_float2(c*v[r].x + s*w.y, c*v[r].y - s*w.x);
        }
      }
    }
  }
}

// One sim14 layer = 32 gates. cs[g] = (cos(th/2), sin(th/2)).
__device__ __forceinline__ void sim32(float2 v[4], int lane, const float2* __restrict__ cs){
  constexpr int KIND[32] = {0,0,0,0,0,0,0,0, 1,1,1,1,1,1,1,1, 0,0,0,0,0,0,0,0, 1,1,1,1,1,1,1,1};
  constexpr int CB[32]   = {0,0,0,0,0,0,0,0, 0,1,2,3,4,5,6,7, 0,0,0,0,0,0,0,0, 0,7,6,5,4,3,2,1};
  constexpr int TB[32]   = {7,6,5,4,3,2,1,0, 7,0,1,2,3,4,5,6, 7,6,5,4,3,2,1,0, 1,0,7,6,5,4,3,2};
  #pragma unroll
  for (int g = 0; g < 32; ++g){
    float2 p = cs[g];
    apply_gate(v, lane, KIND[g], CB[g], TB[g], p.x, p.y);
  }
}

// measurement of one qubit with bit t: wave-reduced xr, xi, zz
__device__ __forceinline__ void measure_one(const float2 v[4], int lane, int t,
                                            float& xr, float& xi, float& zz){
  xr = 0.f; xi = 0.f; zz = 0.f;
  if (t == 7){
    #pragma unroll
    for (int r = 0; r < 2; ++r){
      float2 a0 = v[r], a1 = v[r+2];
      xr += a0.x*a1.x + a0.y*a1.y;
      xi += a0.x*a1.y - a0.y*a1.x;
      zz += (a0.x*a0.x + a0.y*a0.y) - (a1.x*a1.x + a1.y*a1.y);
    }
  } else if (t == 6){
    #pragma unroll
    for (int r = 0; r < 4; r += 2){
      float2 a0 = v[r], a1 = v[r+1];
      xr += a0.x*a1.x + a0.y*a1.y;
      xi += a0.x*a1.y - a0.y*a1.x;
      zz += (a0.x*a0.x + a0.y*a0.y) - (a1.x*a1.x + a1.y*a1.y);
    }
  } else {
    int m = 1 << t;
    #pragma unroll
    for (int r = 0; r < 4; ++r){
      float2 a = v[r];
      float2 w = shfl2(a, m);
      if (!(lane & m)){
        xr += a.x*w.x + a.y*w.y;
        xi += a.x*w.y - a.y*w.x;
        zz += (a.x*a.x + a.y*a.y) - (w.x*w.x + w.y*w.y);
      }
    }
  }
  xr = wave_sum(xr); xi = wave_sum(xi); zz = wave_sum(zz);
}

// ---------- fused prep + degree 1 (256 blocks x 256 threads) ----------
// K split 4-way across waves for the 512-dot (4x the MLP of the 1-wave version);
// circuit runs on wave 0 only.
__global__ __launch_bounds__(256) void k_pd1(
    const int* __restrict__ x, const float* __restrict__ embW,
    const float* __restrict__ e2rW, const float* __restrict__ e2rb,
    const float* __restrict__ mixri, const float* __restrict__ qff,
    float* __restrict__ wcs, float* __restrict__ qcs, float2* __restrict__ S1)
{
  const int p = blockIdx.x;    // 0..255 = b*16+w
  const int t = threadIdx.x;
  const int j = t & 63;        // rotation index
  const int kq = t >> 6;       // K-quarter
  __shared__ float part[4][64];
  __shared__ float2 cs[64];

  {
    const int tok = x[p];
    const float4* er = (const float4*)(embW + (size_t)tok * EMBN) + kq*32;
    const float4* wr = (const float4*)(e2rW + (size_t)j * EMBN) + kq*32;
    float acc = 0.f;
    #pragma unroll 4
    for (int k = 0; k < 32; ++k){
      float4 e = er[k], w4 = wr[k];
      acc += e.x*w4.x + e.y*w4.y + e.z*w4.z + e.w*w4.w;
    }
    part[kq][j] = acc;
  }
  __syncthreads();

  if (t < 64){
    float a = part[0][j] + part[1][j] + part[2][j] + part[3][j] + e2rb[j];
    float th = 0.5f * a;
    float2 c2 = make_float2(cosf(th), sinf(th));
    cs[j] = c2;
    ((float2*)wcs)[p*64 + j] = c2;          // for degrees 2,3
    if (p == 0 && j < 32){ float tq = 0.5f * qff[j]; ((float2*)qcs)[j] = make_float2(cosf(tq), sinf(tq)); }
  }
  __syncthreads();

  if (t < 64){
    const int lane = j;
    float2 v[4];
    v[0] = make_float2(lane == 0 ? 1.f : 0.f, 0.f);
    v[1] = v[2] = v[3] = make_float2(0.f, 0.f);
    sim32(v, lane, cs);
    sim32(v, lane, cs + 32);

    float ssum = 0.f;
    #pragma unroll
    for (int i = 0; i < 16; ++i){
      float mr = mixri[2*i], mi = mixri[2*i+1];
      ssum += sqrtf(mr*mr + mi*mi);
    }
    ssum = fmaxf(ssum, 1e-12f);
    const int w = p & 15;
    const float2 coef = make_float2(mixri[2*w]/ssum, mixri[2*w+1]/ssum);
    #pragma unroll
    for (int r = 0; r < 4; ++r){
      float2 a = v[r];
      S1[p*DIM + ((r<<6) | lane)] = make_float2(coef.x*a.x - coef.y*a.y, coef.x*a.y + coef.y*a.x);
    }
  }
}

// ---------- degree d (d=2,3): reduce previous staging -> circuit -> staging ----------
// 256 threads: 4 waves each partial-sum 4 words into LDS; wave 0 finishes,
// runs the circuit, and writes the staged output.
__global__ __launch_bounds__(256) void k_deg(
    const float2* __restrict__ Sin, float2* __restrict__ Sout,
    const float* __restrict__ wcs, const float* __restrict__ mixri,
    const float* __restrict__ poly, float2* __restrict__ accs, int dprev)
{
  const int p = blockIdx.x, t = threadIdx.x;
  const int b = p >> 4, w = p & 15;
  const int lane = t & 63, wv = t >> 6;
  __shared__ float2 part[4][DIM];   // 8 KB

  {
    float2 v[4];
    v[0] = v[1] = v[2] = v[3] = make_float2(0.f, 0.f);
    const float2* base = Sin + b*NW*DIM;
    #pragma unroll
    for (int k = 0; k < 4; ++k){
      const int ww = wv*4 + k;
      #pragma unroll
      for (int r = 0; r < 4; ++r){
        float2 a = base[ww*DIM + ((r<<6) | lane)];
        v[r].x += a.x; v[r].y += a.y;
      }
    }
    #pragma unroll
    for (int r = 0; r < 4; ++r) part[wv][(r<<6) | lane] = v[r];
  }
  __syncthreads();

  if (t < 64){
    float2 v[4];
    #pragma unroll
    for (int r = 0; r < 4; ++r){
      const int idx = (r<<6) | lane;
      float2 s0 = part[0][idx], s1 = part[1][idx], s2 = part[2][idx], s3 = part[3][idx];
      v[r] = make_float2(s0.x+s1.x+s2.x+s3.x, s0.y+s1.y+s2.y+s3.y);
    }
    if (w == 0){
      const float pd = poly[dprev];
      #pragma unroll
      for (int r = 0; r < 4; ++r){
        const int idx = (r<<6) | lane;
        float2 cur = make_float2(pd*v[r].x, pd*v[r].y);
        if (dprev == 1){
          if (idx == 0) cur.x += poly[0];
          accs[b*DIM + idx] = cur;
        } else {
          float2 old = accs[b*DIM + idx];
          accs[b*DIM + idx] = make_float2(old.x + cur.x, old.y + cur.y);
        }
      }
    }
    const float2* mycs = ((const float2*)wcs) + p*64;
    sim32(v, lane, mycs);
    sim32(v, lane, mycs + 32);
    float ssum = 0.f;
    #pragma unroll
    for (int i = 0; i < 16; ++i){
      float mr = mixri[2*i], mi = mixri[2*i+1];
      ssum += sqrtf(mr*mr + mi*mi);
    }
    ssum = fmaxf(ssum, 1e-12f);
    const float2 coef = make_float2(mixri[2*w]/ssum, mixri[2*w+1]/ssum);
    #pragma unroll
    for (int r = 0; r < 4; ++r){
      float2 a = v[r];
      Sout[p*DIM + ((r<<6) | lane)] = make_float2(coef.x*a.x - coef.y*a.y, coef.x*a.y + coef.y*a.x);
    }
  }
}

// ---------- final: mix, norm, qff circuit, measure, ff1 -> h (bf16, b-major) ----------
__global__ __launch_bounds__(512) void k_final(
    const float2* __restrict__ Sin, const float2* __restrict__ accs,
    const float* __restrict__ poly, const float* __restrict__ qcs,
    const float* __restrict__ ff1W, const float* __restrict__ ff1b,
    __hip_bfloat16* __restrict__ hbf, float* __restrict__ fprobs)
{
  const int b = blockIdx.x, tid = threadIdx.x;
  const int w = tid >> 6, lane = tid & 63;
  __shared__ float2 work[DIM];
  __shared__ float  red[8];
  __shared__ float  exps[24];
  __shared__ float  inv_s;
  __shared__ float  ff1_lds[EMBN*24];   // 48 KB

  { // stage ff1W coalesced: 3072 float4 over 512 threads
    const float4* f4 = (const float4*)ff1W;
    float4* d4 = (float4*)ff1_lds;
    #pragma unroll
    for (int i = 0; i < 6; ++i) d4[i*512 + tid] = f4[i*512 + tid];
  }
  const float psum = fabsf(poly[0]) + fabsf(poly[1]) + fabsf(poly[2]) + fabsf(poly[3]);
  float ssl = 0.f;
  if (tid < DIM){
    float2 s = make_float2(0.f, 0.f);
    const float2* base = Sin + b*NW*DIM;
    #pragma unroll
    for (int ww = 0; ww < NW; ++ww){ float2 a = base[ww*DIM + tid]; s.x += a.x; s.y += a.y; }
    float2 ac = accs[b*DIM + tid];
    const float p3 = poly[3];
    s = make_float2((ac.x + p3*s.x)/psum, (ac.y + p3*s.y)/psum);
    work[tid] = s;
    ssl = s.x*s.x + s.y*s.y;
  }
  ssl = wave_sum(ssl);
  if (lane == 0) red[w] = ssl;
  __syncthreads();
  if (tid == 0){
    float fp = sqrtf(red[0] + red[1] + red[2] + red[3]);
    fprobs[b] = fp;
    inv_s = 1.f / fmaxf(fp, 1e-12f);
  }
  __syncthreads();
  { // waves 0..7 redundantly run the qff circuit; wave w measures qubit w
    const float inv = inv_s;
    float2 v[4];
    #pragma unroll
    for (int r = 0; r < 4; ++r){
      float2 m = work[(r<<6) | lane];
      v[r] = make_float2(m.x*inv, m.y*inv);
    }
    sim32(v, lane, (const float2*)qcs);
    float xr, xi, zz;
    measure_one(v, lane, 7 - w, xr, xi, zz);
    if (lane == 0){ exps[w] = 2.f*xr; exps[8+w] = 2.f*xi; exps[16+w] = zz; }
  }
  __syncthreads();
  float a = ff1b[tid];
  const float* wr = ff1_lds + tid*24;
  #pragma unroll
  for (int m2 = 0; m2 < 24; ++m2) a += exps[m2]*wr[m2];
  hbf[b*EMBN + tid] = __float2bfloat16(fmaxf(a, 0.f));   // b-major bf16 h
}

// ---------- k_out: MFMA GEMM  C[50257x16] = ff2W[50257x512] * h^T ----------
// One 16x16 tile per wave; B (h) entirely in VGPRs; A loaded fp32 from ff2W
// (dense lines) and cvt'd to bf16 in flight. Epilogue: per-wave LDS transpose
// (wave-internal, no barrier) -> one coalesced dwordx4 store per lane.
__global__ __launch_bounds__(256) void k_out(
    const __hip_bfloat16* __restrict__ hbf, const float* __restrict__ ff2W,
    const float* __restrict__ ff2b, const float* __restrict__ fprobs,
    float* __restrict__ out)
{
  __shared__ float tile[4][16][17];   // [wave][n(batch)][m(vocab-in-tile)] + pad
  const int tid = threadIdx.x;
  const int w = tid >> 6, lane = tid & 63;
  const int tileid = blockIdx.x*4 + w;

  if (blockIdx.x == 0 && tid == 0){
    float s = 0.f;
    #pragma unroll
    for (int i = 0; i < 16; ++i) s += fprobs[i];
    out[(size_t)NB*VOCABN] = s * (1.f/16.f);
  }

  const int n = lane & 15;        // batch col (B) / row-in-tile (A)
  const int quad = lane >> 4;     // k-subchunk selector

  // B fragments: B[n=lane&15][k=quad*8+j] ; hbf is [b][k] b-major
  short8 bfrag[16];
  {
    const short* hb = (const short*)hbf + n*EMBN;
    #pragma unroll
    for (int f = 0; f < 16; ++f)
      bfrag[f] = *(const short8*)(hb + f*32 + quad*8);
  }

  if (tileid >= NTILES) return;
  const int tbase = tileid * 16;
  int row = tbase + n; if (row > VOCABN-1) row = VOCABN-1;   // clamp tail loads
  const float* ar = ff2W + (size_t)row * EMBN + quad*8;

  f32x4 acc = {0.f, 0.f, 0.f, 0.f};
  #pragma unroll
  for (int f = 0; f < 16; ++f){
    float4 a0 = *(const float4*)(ar + f*32);
    float4 a1 = *(const float4*)(ar + f*32 + 4);
    short8 af;
    af[0] = f2bf(a0.x); af[1] = f2bf(a0.y); af[2] = f2bf(a0.z); af[3] = f2bf(a0.w);
    af[4] = f2bf(a1.x); af[5] = f2bf(a1.y); af[6] = f2bf(a1.z); af[7] = f2bf(a1.w);
    acc = __builtin_amdgcn_mfma_f32_16x16x32_bf16(af, bfrag[f], acc, 0, 0, 0);
  }

  // C layout: col(n=batch) = lane&15, row(m) = quad*4 + r. Add bias, transpose in LDS.
  #pragma unroll
  for (int r = 0; r < 4; ++r){
    const int m = quad*4 + r;
    const int v = tbase + m;
    const float bias = ff2b[(v < VOCABN) ? v : (VOCABN-1)];
    tile[w][n][m] = acc[r] + bias;
  }
  // wave-internal RAW: compiler inserts lgkmcnt wait; no cross-wave sharing.
  __builtin_amdgcn_wave_barrier();

  const int n2 = lane >> 2;       // batch row
  const int mg = lane & 3;        // m-group of 4
  const int v0 = tbase + mg*4;
  if (tbase + 15 < VOCABN){
    float4 o = make_float4(tile[w][n2][mg*4+0], tile[w][n2][mg*4+1],
                           tile[w][n2][mg*4+2], tile[w][n2][mg*4+3]);
    *(float4*)(out + (size_t)n2*VOCABN + v0) = o;
  } else {
    #pragma unroll
    for (int k = 0; k < 4; ++k){
      const int v = v0 + k;
      if (v < VOCABN) out[(size_t)n2*VOCABN + v] = tile[w][n2][mg*4+k];
    }
  }
}

extern "C" void kernel_launch(void* const* d_in, const int* in_sizes, int n_in,
                              void* d_out, int out_size, void* d_ws, size_t ws_size,
                              hipStream_t stream)
{
  const int*   x     = (const int*)  d_in[0];
  const float* embW  = (const float*)d_in[1];
  const float* e2rW  = (const float*)d_in[2];
  const float* e2rb  = (const float*)d_in[3];
  const float* poly  = (const float*)d_in[4];
  const float* mixri = (const float*)d_in[5];
  const float* qff   = (const float*)d_in[6];
  const float* ff1W  = (const float*)d_in[7];
  const float* ff1b  = (const float*)d_in[8];
  const float* ff2W  = (const float*)d_in[9];
  const float* ff2b  = (const float*)d_in[10];
  float* out = (float*)d_out;
  float* ws  = (float*)d_ws;

  float*  wcs    = ws;             // 32768 floats
  float*  qcs    = ws + 32768;     // 64
  __hip_bfloat16* hbf = (__hip_bfloat16*)(ws + 32832);  // 8192 bf16 = 4096 floats
  float*  fprobs = ws + 36928;     // 16
  float2* accs   = (float2*)(ws + 36944);   // 8192 floats
  float2* S1     = (float2*)(ws + 45136);   // 131072 floats
  float2* S2     = (float2*)(ws + 176208);  // 131072 floats

  k_pd1  <<<256, 256, 0, stream>>>(x, embW, e2rW, e2rb, mixri, qff, wcs, qcs, S1);
  k_deg  <<<256, 256, 0, stream>>>(S1, S2, wcs, mixri, poly, accs, 1);
  k_deg  <<<256, 256, 0, stream>>>(S2, S1, wcs, mixri, poly, accs, 2);
  k_final<<<NB, 512, 0, stream>>>(S1, accs, poly, qcs, ff1W, ff1b, hbf, fprobs);
  k_out  <<<(NTILES + 3)/4, 256, 0, stream>>>(hbf, ff2W, ff2b, fprobs, out);
}